// Round 1
// baseline (2756.818 us; speedup 1.0000x reference)
//
#include <hip/hip_runtime.h>
#include <math.h>

typedef unsigned int u32;
typedef unsigned long long u64;

#define Bc 128
#define Dc 1024
#define Hc 131072
#define Oc 1024
#define Rc 512

#define NBINS 4096
#define NSUB 4
#define CAP 6144

// ws layout in 4-byte units
#define WS_SCORES ((size_t)0)
#define WS_HIST   ((size_t)Bc * Hc)                       // 16,777,216
#define WS_THR    (WS_HIST + (size_t)Bc * NSUB * NBINS)   // +2,097,152
#define WS_SEL    (WS_THR + (size_t)Bc * 4)
#define WS_PART   (WS_SEL + (size_t)Bc * Rc)
// total = WS_PART + Bc*4*Oc = ~19.5M u32 = ~78 MB scratch

__device__ __forceinline__ u32 mono_key(float f) {
    u32 u = __float_as_uint(f);
    return (u & 0x80000000u) ? ~u : (u | 0x80000000u);
}

// ---------------- K1: S[b][h] = sum_d x[b][d] * Win[h][d]  (fp32) ----------------
// Tile: 128 b x 128 h per block, BK=16. 256 threads, each owns 8x8 micro-tile.
__global__ __launch_bounds__(256) void k1_scores(const float* __restrict__ x,
                                                 const float* __restrict__ Win,
                                                 float* __restrict__ S) {
    __shared__ float xs[16][132];   // [k][b], +4 pad
    __shared__ float wls[16][132];  // [k][h], +4 pad
    const int tid = threadIdx.x;
    const int h0 = blockIdx.x * 128;
    const int ty = tid >> 4;   // 0..15  b-group
    const int tx = tid & 15;   // 0..15  h-group

    float acc[8][8];
#pragma unroll
    for (int i = 0; i < 8; ++i)
#pragma unroll
        for (int j = 0; j < 8; ++j) acc[i][j] = 0.0f;

    for (int k0 = 0; k0 < Dc; k0 += 16) {
        // load x chunk: 128 b x 16 k = 2048 floats -> 2 float4 per thread
#pragma unroll
        for (int j = 0; j < 2; ++j) {
            int lin = tid + 256 * j;            // 0..511
            int b  = lin >> 2;                  // 0..127
            int kk = (lin & 3) << 2;            // 0,4,8,12
            float4 v = *reinterpret_cast<const float4*>(&x[(size_t)b * Dc + k0 + kk]);
            xs[kk + 0][b] = v.x; xs[kk + 1][b] = v.y;
            xs[kk + 2][b] = v.z; xs[kk + 3][b] = v.w;
        }
        // load W chunk: 128 h x 16 k
#pragma unroll
        for (int j = 0; j < 2; ++j) {
            int lin = tid + 256 * j;
            int hh = lin >> 2;
            int kk = (lin & 3) << 2;
            float4 v = *reinterpret_cast<const float4*>(&Win[(size_t)(h0 + hh) * Dc + k0 + kk]);
            wls[kk + 0][hh] = v.x; wls[kk + 1][hh] = v.y;
            wls[kk + 2][hh] = v.z; wls[kk + 3][hh] = v.w;
        }
        __syncthreads();
#pragma unroll
        for (int kk = 0; kk < 16; ++kk) {
            float xv[8], wv[8];
            *reinterpret_cast<float4*>(&xv[0]) = *reinterpret_cast<const float4*>(&xs[kk][ty * 8]);
            *reinterpret_cast<float4*>(&xv[4]) = *reinterpret_cast<const float4*>(&xs[kk][ty * 8 + 4]);
            *reinterpret_cast<float4*>(&wv[0]) = *reinterpret_cast<const float4*>(&wls[kk][tx * 8]);
            *reinterpret_cast<float4*>(&wv[4]) = *reinterpret_cast<const float4*>(&wls[kk][tx * 8 + 4]);
#pragma unroll
            for (int i = 0; i < 8; ++i)
#pragma unroll
                for (int j = 0; j < 8; ++j)
                    acc[i][j] = fmaf(xv[i], wv[j], acc[i][j]);
        }
        __syncthreads();
    }
    // write out
#pragma unroll
    for (int i = 0; i < 8; ++i) {
        float* row = &S[(size_t)(ty * 8 + i) * Hc + h0 + tx * 8];
        float4 v0 = make_float4(acc[i][0], acc[i][1], acc[i][2], acc[i][3]);
        float4 v1 = make_float4(acc[i][4], acc[i][5], acc[i][6], acc[i][7]);
        *reinterpret_cast<float4*>(row + 0) = v0;
        *reinterpret_cast<float4*>(row + 4) = v1;
    }
}

// ---------------- K2a: per-row histogram over monotonic score bits ----------------
__global__ __launch_bounds__(1024) void k2a_hist(const float* __restrict__ S,
                                                 u32* __restrict__ hist) {
    __shared__ u32 lh[NSUB][NBINS];  // 64 KB
    const int b = blockIdx.x;
    const int tid = threadIdx.x;
    for (int i = tid; i < NSUB * NBINS; i += 1024) ((u32*)lh)[i] = 0;
    __syncthreads();
    const float* row = S + (size_t)b * Hc;
    const int sub = tid & (NSUB - 1);
    for (int i = tid; i < Hc; i += 1024) {
        u32 bin = mono_key(row[i]) >> 20;   // 12 bits
        atomicAdd(&lh[sub][bin], 1u);
    }
    __syncthreads();
    u32* out = hist + (size_t)b * NSUB * NBINS;
    for (int i = tid; i < NSUB * NBINS; i += 1024) out[i] = ((u32*)lh)[i];
}

// ---------------- K2b: find threshold bin per row ----------------
__global__ __launch_bounds__(256) void k2b_thresh(const u32* __restrict__ hist,
                                                  u32* __restrict__ thr) {
    __shared__ u32 h[NBINS];
    __shared__ u32 csum[64];
    const int b = blockIdx.x;
    const int tid = threadIdx.x;
    const u32* hb = hist + (size_t)b * NSUB * NBINS;
    for (int i = tid; i < NBINS; i += 256) {
        u32 s = 0;
        for (int c = 0; c < NSUB; ++c) s += hb[c * NBINS + i];
        h[i] = s;
    }
    __syncthreads();
    if (tid < 64) {
        u32 s = 0;
        for (int j = 0; j < 64; ++j) s += h[tid * 64 + j];
        csum[tid] = s;
    }
    __syncthreads();
    if (tid == 0) {
        u32 cum = 0;
        int c;
        for (c = 63; c >= 0; --c) {
            if (cum + csum[c] >= (u32)Rc) break;
            cum += csum[c];
        }
        int bin_t = 0; u32 above = 0;
        for (int j = 63; j >= 0; --j) {
            int bin = c * 64 + j;
            if (cum + h[bin] >= (u32)Rc) { bin_t = bin; above = cum; break; }
            cum += h[bin];
        }
        u32* t = thr + (size_t)b * 4;
        t[0] = (u32)bin_t;
        t[1] = above;
        t[2] = (u32)Rc - above;   // need from boundary bin, >=1
    }
}

// ---------------- K2c: select exact top-R indices ----------------
__global__ __launch_bounds__(1024) void k2c_select(const float* __restrict__ S,
                                                   const u32* __restrict__ thr,
                                                   u32* __restrict__ selidx) {
    __shared__ u64 cand[CAP];       // 48 KB
    __shared__ u32 sel[Rc];
    __shared__ u32 cnt_sel, cnt_cand;
    const int b = blockIdx.x;
    const int tid = threadIdx.x;
    if (tid == 0) { cnt_sel = 0; cnt_cand = 0; }
    __syncthreads();
    const u32 bin_t = thr[(size_t)b * 4 + 0];
    const u32 need  = thr[(size_t)b * 4 + 2];
    const float* row = S + (size_t)b * Hc;
    for (int i = tid; i < Hc; i += 1024) {
        u32 u = mono_key(row[i]);
        u32 bin = u >> 20;
        if (bin > bin_t) {
            u32 p = atomicAdd(&cnt_sel, 1u);
            sel[p] = (u32)i;
        } else if (bin == bin_t) {
            u32 p = atomicAdd(&cnt_cand, 1u);
            if (p < CAP) cand[p] = ((u64)u << 32) | (u64)(0xFFFFFFFFu - (u32)i);
        }
    }
    __syncthreads();
    if (tid == 0) {
        int nc = (int)(cnt_cand < (u32)CAP ? cnt_cand : (u32)CAP);
        u32 cs = cnt_sel;
        for (u32 it = 0; it < need; ++it) {
            u64 best = 0; int bj = 0;
            for (int j = 0; j < nc; ++j) {
                u64 v = cand[j];
                if (v > best) { best = v; bj = j; }
            }
            cand[bj] = 0;
            sel[cs++] = 0xFFFFFFFFu - (u32)(best & 0xFFFFFFFFu);
        }
    }
    __syncthreads();
    if (tid < Rc) selidx[(size_t)b * Rc + tid] = sel[tid];
}

// ---------------- K3: partial[b][ch][o] = sum over 128 selected rows ----------------
__global__ __launch_bounds__(256) void k3_gather(const float* __restrict__ S,
                                                 const float* __restrict__ Wout,
                                                 const u32* __restrict__ selidx,
                                                 float* __restrict__ part) {
    __shared__ float g[128];
    __shared__ u32 il[128];
    const int b  = blockIdx.x >> 2;
    const int ch = blockIdx.x & 3;
    const int tid = threadIdx.x;
    if (tid < 128) {
        u32 idx = selidx[(size_t)b * Rc + ch * 128 + tid];
        il[tid] = idx;
        float s = S[(size_t)b * Hc + idx];
        // exact gelu: 0.5*x*(1+erf(x/sqrt(2)))
        g[tid] = 0.5f * s * (1.0f + erff(s * 0.70710678118654752f));
    }
    __syncthreads();
    float4 acc = make_float4(0.f, 0.f, 0.f, 0.f);
    const int o0 = tid * 4;
#pragma unroll 4
    for (int j = 0; j < 128; ++j) {
        float w = g[j];
        float4 v = *reinterpret_cast<const float4*>(&Wout[(size_t)il[j] * Oc + o0]);
        acc.x = fmaf(w, v.x, acc.x);
        acc.y = fmaf(w, v.y, acc.y);
        acc.z = fmaf(w, v.z, acc.z);
        acc.w = fmaf(w, v.w, acc.w);
    }
    *reinterpret_cast<float4*>(&part[((size_t)b * 4 + ch) * Oc + o0]) = acc;
}

// ---------------- K4: reduce 4 partials -> out ----------------
__global__ __launch_bounds__(256) void k4_reduce(const float* __restrict__ part,
                                                 float* __restrict__ out) {
    const int b = blockIdx.x;
    const int o0 = threadIdx.x * 4;
    float4 a = *reinterpret_cast<const float4*>(&part[((size_t)b * 4 + 0) * Oc + o0]);
    float4 c1 = *reinterpret_cast<const float4*>(&part[((size_t)b * 4 + 1) * Oc + o0]);
    float4 c2 = *reinterpret_cast<const float4*>(&part[((size_t)b * 4 + 2) * Oc + o0]);
    float4 c3 = *reinterpret_cast<const float4*>(&part[((size_t)b * 4 + 3) * Oc + o0]);
    a.x += c1.x + c2.x + c3.x;
    a.y += c1.y + c2.y + c3.y;
    a.z += c1.z + c2.z + c3.z;
    a.w += c1.w + c2.w + c3.w;
    *reinterpret_cast<float4*>(&out[(size_t)b * Oc + o0]) = a;
}

extern "C" void kernel_launch(void* const* d_in, const int* in_sizes, int n_in,
                              void* d_out, int out_size, void* d_ws, size_t ws_size,
                              hipStream_t stream) {
    (void)in_sizes; (void)n_in; (void)out_size; (void)ws_size;
    const float* x    = (const float*)d_in[0];
    const float* Win  = (const float*)d_in[1];
    const float* Wout = (const float*)d_in[2];
    float* out = (float*)d_out;

    float* S    = (float*)d_ws + WS_SCORES;
    u32*   hist = (u32*)d_ws + WS_HIST;
    u32*   thr  = (u32*)d_ws + WS_THR;
    u32*   sel  = (u32*)d_ws + WS_SEL;
    float* part = (float*)d_ws + WS_PART;

    k1_scores<<<Hc / 128, 256, 0, stream>>>(x, Win, S);
    k2a_hist<<<Bc, 1024, 0, stream>>>(S, hist);
    k2b_thresh<<<Bc, 256, 0, stream>>>(hist, thr);
    k2c_select<<<Bc, 1024, 0, stream>>>(S, thr, sel);
    k3_gather<<<Bc * 4, 256, 0, stream>>>(S, Wout, sel, part);
    k4_reduce<<<Bc, 256, 0, stream>>>(part, out);
}

// Round 2
// 579.768 us; speedup vs baseline: 4.7550x; 4.7550x over previous
//
#include <hip/hip_runtime.h>
#include <math.h>

typedef unsigned int u32;
typedef unsigned long long u64;

#define Bc 128
#define Dc 1024
#define Hc 131072
#define Oc 1024
#define Rc 512

#define NBINS 4096
#define NSUB 4
#define CAP 6144

// ws layout in 4-byte units
#define WS_SCORES ((size_t)0)
#define WS_HIST   ((size_t)Bc * Hc)                       // 16,777,216
#define WS_THR    (WS_HIST + (size_t)Bc * NSUB * NBINS)   // +2,097,152
#define WS_SEL    (WS_THR + (size_t)Bc * 4)
#define WS_PART   (WS_SEL + (size_t)Bc * Rc)
// total = WS_PART + Bc*4*Oc = ~19.5M u32 = ~78 MB scratch

__device__ __forceinline__ u32 mono_key(float f) {
    u32 u = __float_as_uint(f);
    return (u & 0x80000000u) ? ~u : (u | 0x80000000u);
}

// ---------------- K1: S[b][h] = sum_d x[b][d] * Win[h][d]  (fp32) ----------------
// Tile: 128 b x 128 h per block, BK=16. 256 threads, each owns 8x8 micro-tile.
__global__ __launch_bounds__(256) void k1_scores(const float* __restrict__ x,
                                                 const float* __restrict__ Win,
                                                 float* __restrict__ S) {
    __shared__ float xs[16][132];   // [k][b], +4 pad
    __shared__ float wls[16][132];  // [k][h], +4 pad
    const int tid = threadIdx.x;
    const int h0 = blockIdx.x * 128;
    const int ty = tid >> 4;   // 0..15  b-group
    const int tx = tid & 15;   // 0..15  h-group

    float acc[8][8];
#pragma unroll
    for (int i = 0; i < 8; ++i)
#pragma unroll
        for (int j = 0; j < 8; ++j) acc[i][j] = 0.0f;

    for (int k0 = 0; k0 < Dc; k0 += 16) {
        // load x chunk: 128 b x 16 k = 2048 floats -> 2 float4 per thread
#pragma unroll
        for (int j = 0; j < 2; ++j) {
            int lin = tid + 256 * j;            // 0..511
            int b  = lin >> 2;                  // 0..127
            int kk = (lin & 3) << 2;            // 0,4,8,12
            float4 v = *reinterpret_cast<const float4*>(&x[(size_t)b * Dc + k0 + kk]);
            xs[kk + 0][b] = v.x; xs[kk + 1][b] = v.y;
            xs[kk + 2][b] = v.z; xs[kk + 3][b] = v.w;
        }
        // load W chunk: 128 h x 16 k
#pragma unroll
        for (int j = 0; j < 2; ++j) {
            int lin = tid + 256 * j;
            int hh = lin >> 2;
            int kk = (lin & 3) << 2;
            float4 v = *reinterpret_cast<const float4*>(&Win[(size_t)(h0 + hh) * Dc + k0 + kk]);
            wls[kk + 0][hh] = v.x; wls[kk + 1][hh] = v.y;
            wls[kk + 2][hh] = v.z; wls[kk + 3][hh] = v.w;
        }
        __syncthreads();
#pragma unroll
        for (int kk = 0; kk < 16; ++kk) {
            float xv[8], wv[8];
            *reinterpret_cast<float4*>(&xv[0]) = *reinterpret_cast<const float4*>(&xs[kk][ty * 8]);
            *reinterpret_cast<float4*>(&xv[4]) = *reinterpret_cast<const float4*>(&xs[kk][ty * 8 + 4]);
            *reinterpret_cast<float4*>(&wv[0]) = *reinterpret_cast<const float4*>(&wls[kk][tx * 8]);
            *reinterpret_cast<float4*>(&wv[4]) = *reinterpret_cast<const float4*>(&wls[kk][tx * 8 + 4]);
#pragma unroll
            for (int i = 0; i < 8; ++i)
#pragma unroll
                for (int j = 0; j < 8; ++j)
                    acc[i][j] = fmaf(xv[i], wv[j], acc[i][j]);
        }
        __syncthreads();
    }
    // write out
#pragma unroll
    for (int i = 0; i < 8; ++i) {
        float* row = &S[(size_t)(ty * 8 + i) * Hc + h0 + tx * 8];
        float4 v0 = make_float4(acc[i][0], acc[i][1], acc[i][2], acc[i][3]);
        float4 v1 = make_float4(acc[i][4], acc[i][5], acc[i][6], acc[i][7]);
        *reinterpret_cast<float4*>(row + 0) = v0;
        *reinterpret_cast<float4*>(row + 4) = v1;
    }
}

// ---------------- K2a: per-row histogram over monotonic score bits ----------------
__global__ __launch_bounds__(1024) void k2a_hist(const float* __restrict__ S,
                                                 u32* __restrict__ hist) {
    __shared__ u32 lh[NSUB][NBINS];  // 64 KB
    const int b = blockIdx.x;
    const int tid = threadIdx.x;
    for (int i = tid; i < NSUB * NBINS; i += 1024) ((u32*)lh)[i] = 0;
    __syncthreads();
    const float* row = S + (size_t)b * Hc;
    const int sub = tid & (NSUB - 1);
    for (int i = tid; i < Hc; i += 1024) {
        u32 bin = mono_key(row[i]) >> 20;   // 12 bits
        atomicAdd(&lh[sub][bin], 1u);
    }
    __syncthreads();
    u32* out = hist + (size_t)b * NSUB * NBINS;
    for (int i = tid; i < NSUB * NBINS; i += 1024) out[i] = ((u32*)lh)[i];
}

// ---------------- K2b: find threshold bin per row ----------------
__global__ __launch_bounds__(256) void k2b_thresh(const u32* __restrict__ hist,
                                                  u32* __restrict__ thr) {
    __shared__ u32 h[NBINS];
    __shared__ u32 csum[64];
    const int b = blockIdx.x;
    const int tid = threadIdx.x;
    const u32* hb = hist + (size_t)b * NSUB * NBINS;
    for (int i = tid; i < NBINS; i += 256) {
        u32 s = 0;
        for (int c = 0; c < NSUB; ++c) s += hb[c * NBINS + i];
        h[i] = s;
    }
    __syncthreads();
    if (tid < 64) {
        u32 s = 0;
        for (int j = 0; j < 64; ++j) s += h[tid * 64 + j];
        csum[tid] = s;
    }
    __syncthreads();
    if (tid == 0) {
        u32 cum = 0;
        int c;
        for (c = 63; c >= 0; --c) {
            if (cum + csum[c] >= (u32)Rc) break;
            cum += csum[c];
        }
        int bin_t = 0; u32 above = 0;
        for (int j = 63; j >= 0; --j) {
            int bin = c * 64 + j;
            if (cum + h[bin] >= (u32)Rc) { bin_t = bin; above = cum; break; }
            cum += h[bin];
        }
        u32* t = thr + (size_t)b * 4;
        t[0] = (u32)bin_t;
        t[1] = above;
        t[2] = (u32)Rc - above;   // need from boundary bin, >=1
    }
}

// ---------------- K2c: select exact top-R indices (parallel rank) ----------------
// top[] holds keys of elements strictly above the boundary bin (count < Rc).
// cand[] holds boundary-bin keys. Composite key (mono_score<<32 | ~idx) is
// unique, so rank = |{k : key_k > key_j}| is a bijection onto 0..n-1.
// sel[] comes out fully sorted descending -> deterministic & matches top_k order.
__global__ __launch_bounds__(1024) void k2c_select(const float* __restrict__ S,
                                                   const u32* __restrict__ thr,
                                                   u32* __restrict__ selidx) {
    __shared__ u64 top[Rc];         // 4 KB
    __shared__ u64 cand[CAP];       // 48 KB
    __shared__ u32 cnt_top, cnt_cand;
    const int b = blockIdx.x;
    const int tid = threadIdx.x;
    if (tid == 0) { cnt_top = 0; cnt_cand = 0; }
    __syncthreads();
    const u32 bin_t = thr[(size_t)b * 4 + 0];
    const u32 need  = thr[(size_t)b * 4 + 2];
    const float* row = S + (size_t)b * Hc;
    for (int i = tid; i < Hc; i += 1024) {
        u32 u = mono_key(row[i]);
        u32 bin = u >> 20;
        if (bin > bin_t) {
            u32 p = atomicAdd(&cnt_top, 1u);
            top[p] = ((u64)u << 32) | (u64)(0xFFFFFFFFu - (u32)i);
        } else if (bin == bin_t) {
            u32 p = atomicAdd(&cnt_cand, 1u);
            if (p < CAP) cand[p] = ((u64)u << 32) | (u64)(0xFFFFFFFFu - (u32)i);
        }
    }
    __syncthreads();
    const int ntop = (int)cnt_top;                               // == above < Rc
    const int nc   = (int)(cnt_cand < (u32)CAP ? cnt_cand : (u32)CAP);
    u32* sel = selidx + (size_t)b * Rc;
    // rank the above-threshold winners (<=511 elems, broadcast LDS reads)
    for (int j = tid; j < ntop; j += 1024) {
        u64 my = top[j];
        u32 r = 0;
        for (int k = 0; k < ntop; ++k) r += (top[k] > my) ? 1u : 0u;
        sel[r] = 0xFFFFFFFFu - (u32)(my & 0xFFFFFFFFu);
    }
    // rank the boundary-bin candidates; keep the `need` largest
    for (int j = tid; j < nc; j += 1024) {
        u64 my = cand[j];
        u32 r = 0;
        for (int k = 0; k < nc; ++k) r += (cand[k] > my) ? 1u : 0u;
        if (r < need) sel[ntop + r] = 0xFFFFFFFFu - (u32)(my & 0xFFFFFFFFu);
    }
}

// ---------------- K3: partial[b][ch][o] = sum over 128 selected rows ----------------
__global__ __launch_bounds__(256) void k3_gather(const float* __restrict__ S,
                                                 const float* __restrict__ Wout,
                                                 const u32* __restrict__ selidx,
                                                 float* __restrict__ part) {
    __shared__ float g[128];
    __shared__ u32 il[128];
    const int b  = blockIdx.x >> 2;
    const int ch = blockIdx.x & 3;
    const int tid = threadIdx.x;
    if (tid < 128) {
        u32 idx = selidx[(size_t)b * Rc + ch * 128 + tid];
        il[tid] = idx;
        float s = S[(size_t)b * Hc + idx];
        // exact gelu: 0.5*x*(1+erf(x/sqrt(2)))
        g[tid] = 0.5f * s * (1.0f + erff(s * 0.70710678118654752f));
    }
    __syncthreads();
    float4 acc = make_float4(0.f, 0.f, 0.f, 0.f);
    const int o0 = tid * 4;
#pragma unroll 4
    for (int j = 0; j < 128; ++j) {
        float w = g[j];
        float4 v = *reinterpret_cast<const float4*>(&Wout[(size_t)il[j] * Oc + o0]);
        acc.x = fmaf(w, v.x, acc.x);
        acc.y = fmaf(w, v.y, acc.y);
        acc.z = fmaf(w, v.z, acc.z);
        acc.w = fmaf(w, v.w, acc.w);
    }
    *reinterpret_cast<float4*>(&part[((size_t)b * 4 + ch) * Oc + o0]) = acc;
}

// ---------------- K4: reduce 4 partials -> out ----------------
__global__ __launch_bounds__(256) void k4_reduce(const float* __restrict__ part,
                                                 float* __restrict__ out) {
    const int b = blockIdx.x;
    const int o0 = threadIdx.x * 4;
    float4 a = *reinterpret_cast<const float4*>(&part[((size_t)b * 4 + 0) * Oc + o0]);
    float4 c1 = *reinterpret_cast<const float4*>(&part[((size_t)b * 4 + 1) * Oc + o0]);
    float4 c2 = *reinterpret_cast<const float4*>(&part[((size_t)b * 4 + 2) * Oc + o0]);
    float4 c3 = *reinterpret_cast<const float4*>(&part[((size_t)b * 4 + 3) * Oc + o0]);
    a.x += c1.x + c2.x + c3.x;
    a.y += c1.y + c2.y + c3.y;
    a.z += c1.z + c2.z + c3.z;
    a.w += c1.w + c2.w + c3.w;
    *reinterpret_cast<float4*>(&out[(size_t)b * Oc + o0]) = a;
}

extern "C" void kernel_launch(void* const* d_in, const int* in_sizes, int n_in,
                              void* d_out, int out_size, void* d_ws, size_t ws_size,
                              hipStream_t stream) {
    (void)in_sizes; (void)n_in; (void)out_size; (void)ws_size;
    const float* x    = (const float*)d_in[0];
    const float* Win  = (const float*)d_in[1];
    const float* Wout = (const float*)d_in[2];
    float* out = (float*)d_out;

    float* S    = (float*)d_ws + WS_SCORES;
    u32*   hist = (u32*)d_ws + WS_HIST;
    u32*   thr  = (u32*)d_ws + WS_THR;
    u32*   sel  = (u32*)d_ws + WS_SEL;
    float* part = (float*)d_ws + WS_PART;

    k1_scores<<<Hc / 128, 256, 0, stream>>>(x, Win, S);
    k2a_hist<<<Bc, 1024, 0, stream>>>(S, hist);
    k2b_thresh<<<Bc, 256, 0, stream>>>(hist, thr);
    k2c_select<<<Bc, 1024, 0, stream>>>(S, thr, sel);
    k3_gather<<<Bc * 4, 256, 0, stream>>>(S, Wout, sel, part);
    k4_reduce<<<Bc, 256, 0, stream>>>(part, out);
}

// Round 3
// 334.581 us; speedup vs baseline: 8.2396x; 1.7328x over previous
//
#include <hip/hip_runtime.h>
#include <math.h>

typedef unsigned int u32;
typedef unsigned long long u64;
typedef _Float16 f16;
typedef f16 half8v __attribute__((ext_vector_type(8)));
typedef float f32x4 __attribute__((ext_vector_type(4)));

#define Bc 128
#define Dc 1024
#define Hc 131072
#define Oc 1024
#define Rc 512

#define NBINS 4096
#define NSUB 4
#define CAP 6144

// ws layout in 4-byte units
#define WS_SCORES ((size_t)0)
#define WS_HIST   ((size_t)Bc * Hc)                       // 16,777,216
#define WS_THR    (WS_HIST + (size_t)Bc * NSUB * NBINS)   // +2,097,152
#define WS_SEL    (WS_THR + (size_t)Bc * 4)
#define WS_PART   (WS_SEL + (size_t)Bc * Rc)
#define WS_XHI    (WS_PART + (size_t)Bc * 4 * Oc)         // x hi split, 131072 f16
#define WS_XLO    (WS_XHI + (size_t)Bc * Dc / 2)          // x lo split
// total ~78.4 MB

__device__ __forceinline__ u32 mono_key(float f) {
    u32 u = __float_as_uint(f);
    return (u & 0x80000000u) ? ~u : (u | 0x80000000u);
}

// ---------------- K0: split x into f16 hi + scaled-lo, pre-swizzled ----------------
// Layout: [kt][row][slot][e], slot = kslot ^ (row&3), matching k1's LDS swizzle,
// so k1's A-staging is a linear coalesced copy.
__global__ __launch_bounds__(512) void kx_split(const float* __restrict__ x,
                                                f16* __restrict__ xhi,
                                                f16* __restrict__ xlo) {
    int c = blockIdx.x * 512 + threadIdx.x;   // 0..16383 chunks of 8
    int row = c >> 7;                         // 0..127
    int kc = c & 127;                         // k-chunk
    const float* src = x + (size_t)row * Dc + kc * 8;
    float4 v0 = *reinterpret_cast<const float4*>(src);
    float4 v1 = *reinterpret_cast<const float4*>(src + 4);
    int kt = kc >> 2;
    int kslot = kc & 3;
    int dst = kt * 4096 + row * 32 + ((kslot ^ (row & 3)) << 3);
    half8v h, l;
#pragma unroll
    for (int e = 0; e < 8; ++e) {
        float f = (e < 4) ? reinterpret_cast<const float*>(&v0)[e]
                          : reinterpret_cast<const float*>(&v1)[e - 4];
        f16 hh = (f16)f;
        h[e] = hh;
        l[e] = (f16)((f - (float)hh) * 2048.0f);
    }
    *reinterpret_cast<half8v*>(xhi + dst) = h;
    *reinterpret_cast<half8v*>(xlo + dst) = l;
}

// ---------------- K1: S = x @ Win^T via f16 split MFMA ----------------
// 128x128 tile, BK=32, 512 threads = 8 waves (2m x 4n), each wave 64x32 out.
// S = acc1(hi*hi) + acc2(hi*lo' + lo'*hi)/2048, error ~ fp32-level.
__global__ __launch_bounds__(512) void k1_mfma(const float* __restrict__ Win,
                                               const f16* __restrict__ xhi,
                                               const f16* __restrict__ xlo,
                                               float* __restrict__ S) {
    __shared__ f16 lds[16384];   // Ahi|Alo|Bhi|Blo, 4 x 128x32, 32 KB
    f16* Ahi = lds;
    f16* Alo = lds + 4096;
    f16* Bhi = lds + 8192;
    f16* Blo = lds + 12288;
    const int tid = threadIdx.x;
    const int h0 = blockIdx.x * 128;
    const int brow = tid >> 2;              // B-tile row (= h col), 0..127
    const int bslot = tid & 3;
    const float* bsrc = Win + (size_t)(h0 + brow) * Dc + bslot * 8;
    const int wB = brow * 32 + ((bslot ^ (brow & 3)) << 3);

    const int lane = tid & 63;
    const int wid = tid >> 6;
    const int wm = wid >> 2;                // 0..1
    const int wn = wid & 3;                 // 0..3
    const int lr = lane & 15;
    const int lk = lane >> 4;               // k-slot for fragment reads

    f32x4 acc1[4][2], acc2[4][2];
#pragma unroll
    for (int i = 0; i < 4; ++i)
#pragma unroll
        for (int j = 0; j < 2; ++j) {
            acc1[i][j] = (f32x4){0.f, 0.f, 0.f, 0.f};
            acc2[i][j] = (f32x4){0.f, 0.f, 0.f, 0.f};
        }

    // prefetch ks=0
    float4 vb0 = *reinterpret_cast<const float4*>(bsrc);
    float4 vb1 = *reinterpret_cast<const float4*>(bsrc + 4);
    half8v ha = *reinterpret_cast<const half8v*>(xhi + tid * 8);
    half8v la = *reinterpret_cast<const half8v*>(xlo + tid * 8);

    for (int ks = 0; ks < 32; ++ks) {
        // convert B chunk (8 elems): hi = f16(f), lo = f16((f-hi)*2048)
        half8v bh, bl;
#pragma unroll
        for (int e = 0; e < 8; ++e) {
            float f = (e < 4) ? reinterpret_cast<const float*>(&vb0)[e]
                              : reinterpret_cast<const float*>(&vb1)[e - 4];
            f16 hh = (f16)f;
            bh[e] = hh;
            bl[e] = (f16)((f - (float)hh) * 2048.0f);
        }
        __syncthreads();   // previous tile fully consumed
        *reinterpret_cast<half8v*>(Ahi + tid * 8) = ha;   // linear (pre-swizzled src)
        *reinterpret_cast<half8v*>(Alo + tid * 8) = la;
        *reinterpret_cast<half8v*>(Bhi + wB) = bh;        // swizzled
        *reinterpret_cast<half8v*>(Blo + wB) = bl;
        __syncthreads();   // tile ready
        if (ks < 31) {     // prefetch next, overlaps MFMA below
            vb0 = *reinterpret_cast<const float4*>(bsrc + (ks + 1) * 32);
            vb1 = *reinterpret_cast<const float4*>(bsrc + (ks + 1) * 32 + 4);
            ha = *reinterpret_cast<const half8v*>(xhi + (ks + 1) * 4096 + tid * 8);
            la = *reinterpret_cast<const half8v*>(xlo + (ks + 1) * 4096 + tid * 8);
        }
        // A fragments for this wave's 4 m-frags
        half8v afh[4], afl[4];
#pragma unroll
        for (int i = 0; i < 4; ++i) {
            int r = wm * 64 + i * 16 + lr;
            int ad = r * 32 + ((lk ^ (r & 3)) << 3);
            afh[i] = *reinterpret_cast<const half8v*>(Ahi + ad);
            afl[i] = *reinterpret_cast<const half8v*>(Alo + ad);
        }
#pragma unroll
        for (int j = 0; j < 2; ++j) {
            int cdx = wn * 32 + j * 16 + lr;
            int bd = cdx * 32 + ((lk ^ (cdx & 3)) << 3);
            half8v bfh = *reinterpret_cast<const half8v*>(Bhi + bd);
            half8v bfl = *reinterpret_cast<const half8v*>(Blo + bd);
#pragma unroll
            for (int i = 0; i < 4; ++i) {
                acc1[i][j] = __builtin_amdgcn_mfma_f32_16x16x32_f16(afh[i], bfh, acc1[i][j], 0, 0, 0);
                acc2[i][j] = __builtin_amdgcn_mfma_f32_16x16x32_f16(afh[i], bfl, acc2[i][j], 0, 0, 0);
                acc2[i][j] = __builtin_amdgcn_mfma_f32_16x16x32_f16(afl[i], bfh, acc2[i][j], 0, 0, 0);
            }
        }
    }
    // epilogue: C/D layout col=lane&15, row=(lane>>4)*4+r  [m89-verified]
#pragma unroll
    for (int i = 0; i < 4; ++i)
#pragma unroll
        for (int j = 0; j < 2; ++j)
#pragma unroll
            for (int r = 0; r < 4; ++r) {
                int row = wm * 64 + i * 16 + lk * 4 + r;
                int col = h0 + wn * 32 + j * 16 + lr;
                S[(size_t)row * Hc + col] = acc1[i][j][r] + acc2[i][j][r] * (1.0f / 2048.0f);
            }
}

// ---------------- K2a: per-row histogram over monotonic score bits ----------------
__global__ __launch_bounds__(1024) void k2a_hist(const float* __restrict__ S,
                                                 u32* __restrict__ hist) {
    __shared__ u32 lh[NSUB][NBINS];  // 64 KB
    const int b = blockIdx.x;
    const int tid = threadIdx.x;
    for (int i = tid; i < NSUB * NBINS; i += 1024) ((u32*)lh)[i] = 0;
    __syncthreads();
    const float* row = S + (size_t)b * Hc;
    const int sub = tid & (NSUB - 1);
    for (int i = tid; i < Hc; i += 1024) {
        u32 bin = mono_key(row[i]) >> 20;   // 12 bits
        atomicAdd(&lh[sub][bin], 1u);
    }
    __syncthreads();
    u32* out = hist + (size_t)b * NSUB * NBINS;
    for (int i = tid; i < NSUB * NBINS; i += 1024) out[i] = ((u32*)lh)[i];
}

// ---------------- K2b: find threshold bin per row ----------------
__global__ __launch_bounds__(256) void k2b_thresh(const u32* __restrict__ hist,
                                                  u32* __restrict__ thr) {
    __shared__ u32 h[NBINS];
    __shared__ u32 csum[64];
    const int b = blockIdx.x;
    const int tid = threadIdx.x;
    const u32* hb = hist + (size_t)b * NSUB * NBINS;
    for (int i = tid; i < NBINS; i += 256) {
        u32 s = 0;
        for (int c = 0; c < NSUB; ++c) s += hb[c * NBINS + i];
        h[i] = s;
    }
    __syncthreads();
    if (tid < 64) {
        u32 s = 0;
        for (int j = 0; j < 64; ++j) s += h[tid * 64 + j];
        csum[tid] = s;
    }
    __syncthreads();
    if (tid == 0) {
        u32 cum = 0;
        int c;
        for (c = 63; c >= 0; --c) {
            if (cum + csum[c] >= (u32)Rc) break;
            cum += csum[c];
        }
        int bin_t = 0; u32 above = 0;
        for (int j = 63; j >= 0; --j) {
            int bin = c * 64 + j;
            if (cum + h[bin] >= (u32)Rc) { bin_t = bin; above = cum; break; }
            cum += h[bin];
        }
        u32* t = thr + (size_t)b * 4;
        t[0] = (u32)bin_t;
        t[1] = above;
        t[2] = (u32)Rc - above;   // need from boundary bin, >=1
    }
}

// ---------------- K2c: select exact top-R indices (parallel rank) ----------------
__global__ __launch_bounds__(1024) void k2c_select(const float* __restrict__ S,
                                                   const u32* __restrict__ thr,
                                                   u32* __restrict__ selidx) {
    __shared__ u64 top[Rc];         // 4 KB
    __shared__ u64 cand[CAP];       // 48 KB
    __shared__ u32 cnt_top, cnt_cand;
    const int b = blockIdx.x;
    const int tid = threadIdx.x;
    if (tid == 0) { cnt_top = 0; cnt_cand = 0; }
    __syncthreads();
    const u32 bin_t = thr[(size_t)b * 4 + 0];
    const u32 need  = thr[(size_t)b * 4 + 2];
    const float* row = S + (size_t)b * Hc;
    for (int i = tid; i < Hc; i += 1024) {
        u32 u = mono_key(row[i]);
        u32 bin = u >> 20;
        if (bin > bin_t) {
            u32 p = atomicAdd(&cnt_top, 1u);
            top[p] = ((u64)u << 32) | (u64)(0xFFFFFFFFu - (u32)i);
        } else if (bin == bin_t) {
            u32 p = atomicAdd(&cnt_cand, 1u);
            if (p < CAP) cand[p] = ((u64)u << 32) | (u64)(0xFFFFFFFFu - (u32)i);
        }
    }
    __syncthreads();
    const int ntop = (int)cnt_top;
    const int nc   = (int)(cnt_cand < (u32)CAP ? cnt_cand : (u32)CAP);
    u32* sel = selidx + (size_t)b * Rc;
    for (int j = tid; j < ntop; j += 1024) {
        u64 my = top[j];
        u32 r = 0;
        for (int k = 0; k < ntop; ++k) r += (top[k] > my) ? 1u : 0u;
        sel[r] = 0xFFFFFFFFu - (u32)(my & 0xFFFFFFFFu);
    }
    for (int j = tid; j < nc; j += 1024) {
        u64 my = cand[j];
        u32 r = 0;
        for (int k = 0; k < nc; ++k) r += (cand[k] > my) ? 1u : 0u;
        if (r < need) sel[ntop + r] = 0xFFFFFFFFu - (u32)(my & 0xFFFFFFFFu);
    }
}

// ---------------- K3: partial[b][ch][o] = sum over 128 selected rows ----------------
__global__ __launch_bounds__(256) void k3_gather(const float* __restrict__ S,
                                                 const float* __restrict__ Wout,
                                                 const u32* __restrict__ selidx,
                                                 float* __restrict__ part) {
    __shared__ float g[128];
    __shared__ u32 il[128];
    const int b  = blockIdx.x >> 2;
    const int ch = blockIdx.x & 3;
    const int tid = threadIdx.x;
    if (tid < 128) {
        u32 idx = selidx[(size_t)b * Rc + ch * 128 + tid];
        il[tid] = idx;
        float s = S[(size_t)b * Hc + idx];
        g[tid] = 0.5f * s * (1.0f + erff(s * 0.70710678118654752f));
    }
    __syncthreads();
    float4 acc = make_float4(0.f, 0.f, 0.f, 0.f);
    const int o0 = tid * 4;
#pragma unroll 4
    for (int j = 0; j < 128; ++j) {
        float w = g[j];
        float4 v = *reinterpret_cast<const float4*>(&Wout[(size_t)il[j] * Oc + o0]);
        acc.x = fmaf(w, v.x, acc.x);
        acc.y = fmaf(w, v.y, acc.y);
        acc.z = fmaf(w, v.z, acc.z);
        acc.w = fmaf(w, v.w, acc.w);
    }
    *reinterpret_cast<float4*>(&part[((size_t)b * 4 + ch) * Oc + o0]) = acc;
}

// ---------------- K4: reduce 4 partials -> out ----------------
__global__ __launch_bounds__(256) void k4_reduce(const float* __restrict__ part,
                                                 float* __restrict__ out) {
    const int b = blockIdx.x;
    const int o0 = threadIdx.x * 4;
    float4 a = *reinterpret_cast<const float4*>(&part[((size_t)b * 4 + 0) * Oc + o0]);
    float4 c1 = *reinterpret_cast<const float4*>(&part[((size_t)b * 4 + 1) * Oc + o0]);
    float4 c2 = *reinterpret_cast<const float4*>(&part[((size_t)b * 4 + 2) * Oc + o0]);
    float4 c3 = *reinterpret_cast<const float4*>(&part[((size_t)b * 4 + 3) * Oc + o0]);
    a.x += c1.x + c2.x + c3.x;
    a.y += c1.y + c2.y + c3.y;
    a.z += c1.z + c2.z + c3.z;
    a.w += c1.w + c2.w + c3.w;
    *reinterpret_cast<float4*>(&out[(size_t)b * Oc + o0]) = a;
}

extern "C" void kernel_launch(void* const* d_in, const int* in_sizes, int n_in,
                              void* d_out, int out_size, void* d_ws, size_t ws_size,
                              hipStream_t stream) {
    (void)in_sizes; (void)n_in; (void)out_size; (void)ws_size;
    const float* x    = (const float*)d_in[0];
    const float* Win  = (const float*)d_in[1];
    const float* Wout = (const float*)d_in[2];
    float* out = (float*)d_out;

    float* S    = (float*)d_ws + WS_SCORES;
    u32*   hist = (u32*)d_ws + WS_HIST;
    u32*   thr  = (u32*)d_ws + WS_THR;
    u32*   sel  = (u32*)d_ws + WS_SEL;
    float* part = (float*)d_ws + WS_PART;
    f16*   xhi  = (f16*)((u32*)d_ws + WS_XHI);
    f16*   xlo  = (f16*)((u32*)d_ws + WS_XLO);

    kx_split<<<32, 512, 0, stream>>>(x, xhi, xlo);
    k1_mfma<<<Hc / 128, 512, 0, stream>>>(Win, xhi, xlo, S);
    k2a_hist<<<Bc, 1024, 0, stream>>>(S, hist);
    k2b_thresh<<<Bc, 256, 0, stream>>>(hist, thr);
    k2c_select<<<Bc, 1024, 0, stream>>>(S, thr, sel);
    k3_gather<<<Bc * 4, 256, 0, stream>>>(S, Wout, sel, part);
    k4_reduce<<<Bc, 256, 0, stream>>>(part, out);
}

// Round 4
// 263.835 us; speedup vs baseline: 10.4490x; 1.2681x over previous
//
#include <hip/hip_runtime.h>
#include <math.h>

typedef unsigned int u32;
typedef unsigned long long u64;
typedef _Float16 f16;
typedef f16 half8v __attribute__((ext_vector_type(8)));
typedef float f32x4 __attribute__((ext_vector_type(4)));

#define Bc 128
#define Dc 1024
#define Hc 131072
#define Oc 1024
#define Rc 512

#define NBINS 4096
#define NSUB 2
#define CAP 6144

// ws layout in 4-byte units
#define WS_SCORES ((size_t)0)
#define WS_THR    ((size_t)Bc * Hc)
#define WS_SEL    (WS_THR + (size_t)Bc * 4)
#define WS_PART   (WS_SEL + (size_t)Bc * Rc)
#define WS_XHI    (WS_PART + (size_t)Bc * 4 * Oc)         // x hi split, 131072 f16
#define WS_XLO    (WS_XHI + (size_t)Bc * Dc / 2)          // x lo split

__device__ __forceinline__ u32 mono_key(float f) {
    u32 u = __float_as_uint(f);
    return (u & 0x80000000u) ? ~u : (u | 0x80000000u);
}

// ---------------- K0: split x into f16 hi + scaled-lo, pre-swizzled ----------------
__global__ __launch_bounds__(512) void kx_split(const float* __restrict__ x,
                                                f16* __restrict__ xhi,
                                                f16* __restrict__ xlo) {
    int c = blockIdx.x * 512 + threadIdx.x;   // 0..16383 chunks of 8
    int row = c >> 7;                         // 0..127
    int kc = c & 127;                         // k-chunk
    const float* src = x + (size_t)row * Dc + kc * 8;
    float4 v0 = *reinterpret_cast<const float4*>(src);
    float4 v1 = *reinterpret_cast<const float4*>(src + 4);
    int kt = kc >> 2;
    int kslot = kc & 3;
    int dst = kt * 4096 + row * 32 + ((kslot ^ (row & 3)) << 3);
    half8v h, l;
#pragma unroll
    for (int e = 0; e < 8; ++e) {
        float f = (e < 4) ? reinterpret_cast<const float*>(&v0)[e]
                          : reinterpret_cast<const float*>(&v1)[e - 4];
        f16 hh = (f16)f;
        h[e] = hh;
        l[e] = (f16)((f - (float)hh) * 2048.0f);
    }
    *reinterpret_cast<half8v*>(xhi + dst) = h;
    *reinterpret_cast<half8v*>(xlo + dst) = l;
}

// ---------------- K1: S = x @ Win^T via f16 split MFMA, double-buffered LDS ----------------
// 128x128 tile, BK=32, 512 threads = 8 waves (2m x 4n). One barrier per K-step.
// S = acc1(hi*hi) + acc2(hi*lo' + lo'*hi)/2048, error ~ fp32-level.
#define AHI 0
#define ALO 4096
#define BHI 8192
#define BLO 12288
__global__ __launch_bounds__(512) void k1_mfma(const float* __restrict__ Win,
                                               const f16* __restrict__ xhi,
                                               const f16* __restrict__ xlo,
                                               float* __restrict__ S) {
    __shared__ f16 lds[2][16384];   // 64 KB: [buf][Ahi|Alo|Bhi|Blo]
    const int tid = threadIdx.x;
    const int h0 = blockIdx.x * 128;
    const int brow = tid >> 2;              // B-tile row (= h col), 0..127
    const int bslot = tid & 3;
    const float* bsrc = Win + (size_t)(h0 + brow) * Dc + bslot * 8;
    const int wB = brow * 32 + ((bslot ^ (brow & 3)) << 3);

    const int lane = tid & 63;
    const int wid = tid >> 6;
    const int wm = wid >> 2;                // 0..1
    const int wn = wid & 3;                 // 0..3
    const int lr = lane & 15;
    const int lk = lane >> 4;               // k-slot for fragment reads

    f32x4 acc1[4][2], acc2[4][2];
#pragma unroll
    for (int i = 0; i < 4; ++i)
#pragma unroll
        for (int j = 0; j < 2; ++j) {
            acc1[i][j] = (f32x4){0.f, 0.f, 0.f, 0.f};
            acc2[i][j] = (f32x4){0.f, 0.f, 0.f, 0.f};
        }

    // prologue: load + convert + write ks=0 into buf0
    {
        float4 vb0 = *reinterpret_cast<const float4*>(bsrc);
        float4 vb1 = *reinterpret_cast<const float4*>(bsrc + 4);
        half8v ha = *reinterpret_cast<const half8v*>(xhi + tid * 8);
        half8v la = *reinterpret_cast<const half8v*>(xlo + tid * 8);
        half8v bh, bl;
#pragma unroll
        for (int e = 0; e < 8; ++e) {
            float f = (e < 4) ? reinterpret_cast<const float*>(&vb0)[e]
                              : reinterpret_cast<const float*>(&vb1)[e - 4];
            f16 hh = (f16)f;
            bh[e] = hh;
            bl[e] = (f16)((f - (float)hh) * 2048.0f);
        }
        f16* L = lds[0];
        *reinterpret_cast<half8v*>(L + AHI + tid * 8) = ha;
        *reinterpret_cast<half8v*>(L + ALO + tid * 8) = la;
        *reinterpret_cast<half8v*>(L + BHI + wB) = bh;
        *reinterpret_cast<half8v*>(L + BLO + wB) = bl;
    }
    __syncthreads();

    for (int ks = 0; ks < 32; ++ks) {
        f16* C = lds[ks & 1];
        f16* N = lds[(ks & 1) ^ 1];
        const bool pf = (ks < 31);
        // issue next-tile global loads early (latency hidden under MFMA)
        float4 nvb0, nvb1;
        half8v nha, nla;
        if (pf) {
            nvb0 = *reinterpret_cast<const float4*>(bsrc + (ks + 1) * 32);
            nvb1 = *reinterpret_cast<const float4*>(bsrc + (ks + 1) * 32 + 4);
            nha = *reinterpret_cast<const half8v*>(xhi + (ks + 1) * 4096 + tid * 8);
            nla = *reinterpret_cast<const half8v*>(xlo + (ks + 1) * 4096 + tid * 8);
        }
        // fragments + MFMA from current buffer
        half8v afh[4], afl[4];
#pragma unroll
        for (int i = 0; i < 4; ++i) {
            int r = wm * 64 + i * 16 + lr;
            int ad = r * 32 + ((lk ^ (r & 3)) << 3);
            afh[i] = *reinterpret_cast<const half8v*>(C + AHI + ad);
            afl[i] = *reinterpret_cast<const half8v*>(C + ALO + ad);
        }
#pragma unroll
        for (int j = 0; j < 2; ++j) {
            int cdx = wn * 32 + j * 16 + lr;
            int bd = cdx * 32 + ((lk ^ (cdx & 3)) << 3);
            half8v bfh = *reinterpret_cast<const half8v*>(C + BHI + bd);
            half8v bfl = *reinterpret_cast<const half8v*>(C + BLO + bd);
#pragma unroll
            for (int i = 0; i < 4; ++i) {
                acc1[i][j] = __builtin_amdgcn_mfma_f32_16x16x32_f16(afh[i], bfh, acc1[i][j], 0, 0, 0);
                acc2[i][j] = __builtin_amdgcn_mfma_f32_16x16x32_f16(afh[i], bfl, acc2[i][j], 0, 0, 0);
                acc2[i][j] = __builtin_amdgcn_mfma_f32_16x16x32_f16(afl[i], bfh, acc2[i][j], 0, 0, 0);
            }
        }
        // convert + write next tile into alternate buffer, single barrier
        if (pf) {
            half8v bh, bl;
#pragma unroll
            for (int e = 0; e < 8; ++e) {
                float f = (e < 4) ? reinterpret_cast<const float*>(&nvb0)[e]
                                  : reinterpret_cast<const float*>(&nvb1)[e - 4];
                f16 hh = (f16)f;
                bh[e] = hh;
                bl[e] = (f16)((f - (float)hh) * 2048.0f);
            }
            *reinterpret_cast<half8v*>(N + AHI + tid * 8) = nha;
            *reinterpret_cast<half8v*>(N + ALO + tid * 8) = nla;
            *reinterpret_cast<half8v*>(N + BHI + wB) = bh;
            *reinterpret_cast<half8v*>(N + BLO + wB) = bl;
            __syncthreads();
        }
    }
    // epilogue: C/D layout col=lane&15, row=(lane>>4)*4+r  [m89-verified]
#pragma unroll
    for (int i = 0; i < 4; ++i)
#pragma unroll
        for (int j = 0; j < 2; ++j)
#pragma unroll
            for (int r = 0; r < 4; ++r) {
                int row = wm * 64 + i * 16 + lk * 4 + r;
                int col = h0 + wn * 32 + j * 16 + lr;
                S[(size_t)row * Hc + col] = acc1[i][j][r] + acc2[i][j][r] * (1.0f / 2048.0f);
            }
}

// ---------------- K2: fused hist + threshold + select (one block per row) ----------------
// Dynamic LDS: lh[NSUB*NBINS] (32KB) | top[512] (4KB) | cand[CAP] (48KB)
#define K2_LDS_BYTES ((NSUB * NBINS) * 4 + Rc * 8 + CAP * 8)
__global__ __launch_bounds__(1024) void k2_select(const float* __restrict__ S,
                                                  u32* __restrict__ selidx) {
    extern __shared__ u32 dyn[];
    u32* lh  = dyn;                               // NSUB*NBINS
    u64* top = (u64*)(dyn + NSUB * NBINS);        // 512
    u64* cand = (u64*)(dyn + NSUB * NBINS + Rc * 2);  // CAP
    __shared__ u32 csum[64];
    __shared__ u32 s_bint, s_need, cnt_top, cnt_cand;

    const int b = blockIdx.x;
    const int tid = threadIdx.x;
    for (int i = tid; i < NSUB * NBINS; i += 1024) lh[i] = 0;
    if (tid == 0) { cnt_top = 0; cnt_cand = 0; }
    __syncthreads();

    const float4* row4 = reinterpret_cast<const float4*>(S + (size_t)b * Hc);
    const int sub = (tid & (NSUB - 1)) * NBINS;
    // phase 1: histogram (vectorized)
    for (int it = 0; it < Hc / 4096; ++it) {
        float4 v = row4[tid + it * 1024];
#pragma unroll
        for (int e = 0; e < 4; ++e) {
            u32 bin = mono_key(reinterpret_cast<const float*>(&v)[e]) >> 20;
            atomicAdd(&lh[sub + bin], 1u);
        }
    }
    __syncthreads();
    // combine sub-hists
    for (int i = tid; i < NBINS; i += 1024) lh[i] += lh[NBINS + i];
    __syncthreads();
    if (tid < 64) {
        u32 s = 0;
        for (int j = 0; j < 64; ++j) s += lh[tid * 64 + j];
        csum[tid] = s;
    }
    __syncthreads();
    if (tid == 0) {
        u32 cum = 0;
        int c;
        for (c = 63; c >= 0; --c) {
            if (cum + csum[c] >= (u32)Rc) break;
            cum += csum[c];
        }
        int bin_t = 0; u32 above = 0;
        for (int j = 63; j >= 0; --j) {
            int bin = c * 64 + j;
            if (cum + lh[bin] >= (u32)Rc) { bin_t = bin; above = cum; break; }
            cum += lh[bin];
        }
        s_bint = (u32)bin_t;
        s_need = (u32)Rc - above;
    }
    __syncthreads();
    const u32 bin_t = s_bint;
    const u32 need  = s_need;
    // phase 2: collect winners + boundary candidates (vectorized)
    for (int it = 0; it < Hc / 4096; ++it) {
        float4 v = row4[tid + it * 1024];
        int i0 = (tid + it * 1024) * 4;
#pragma unroll
        for (int e = 0; e < 4; ++e) {
            u32 u = mono_key(reinterpret_cast<const float*>(&v)[e]);
            u32 bin = u >> 20;
            if (bin > bin_t) {
                u32 p = atomicAdd(&cnt_top, 1u);
                top[p] = ((u64)u << 32) | (u64)(0xFFFFFFFFu - (u32)(i0 + e));
            } else if (bin == bin_t) {
                u32 p = atomicAdd(&cnt_cand, 1u);
                if (p < CAP) cand[p] = ((u64)u << 32) | (u64)(0xFFFFFFFFu - (u32)(i0 + e));
            }
        }
    }
    __syncthreads();
    const int ntop = (int)cnt_top;
    const int nc   = (int)(cnt_cand < (u32)CAP ? cnt_cand : (u32)CAP);
    u32* sel = selidx + (size_t)b * Rc;
    // rank winners (unique composite keys -> bijective ranks, sorted descending)
    for (int j = tid; j < ntop; j += 1024) {
        u64 my = top[j];
        u32 r = 0;
        for (int k = 0; k < ntop; ++k) r += (top[k] > my) ? 1u : 0u;
        sel[r] = 0xFFFFFFFFu - (u32)(my & 0xFFFFFFFFu);
    }
    // rank boundary candidates; keep `need` largest
    for (int j = tid; j < nc; j += 1024) {
        u64 my = cand[j];
        u32 r = 0;
        for (int k = 0; k < nc; ++k) r += (cand[k] > my) ? 1u : 0u;
        if (r < need) sel[ntop + r] = 0xFFFFFFFFu - (u32)(my & 0xFFFFFFFFu);
    }
}

// ---------------- K3: partial[b][ch][o] = sum over 128 selected rows ----------------
__global__ __launch_bounds__(256) void k3_gather(const float* __restrict__ S,
                                                 const float* __restrict__ Wout,
                                                 const u32* __restrict__ selidx,
                                                 float* __restrict__ part) {
    __shared__ float g[128];
    __shared__ u32 il[128];
    const int b  = blockIdx.x >> 2;
    const int ch = blockIdx.x & 3;
    const int tid = threadIdx.x;
    if (tid < 128) {
        u32 idx = selidx[(size_t)b * Rc + ch * 128 + tid];
        il[tid] = idx;
        float s = S[(size_t)b * Hc + idx];
        g[tid] = 0.5f * s * (1.0f + erff(s * 0.70710678118654752f));
    }
    __syncthreads();
    float4 acc = make_float4(0.f, 0.f, 0.f, 0.f);
    const int o0 = tid * 4;
#pragma unroll 4
    for (int j = 0; j < 128; ++j) {
        float w = g[j];
        float4 v = *reinterpret_cast<const float4*>(&Wout[(size_t)il[j] * Oc + o0]);
        acc.x = fmaf(w, v.x, acc.x);
        acc.y = fmaf(w, v.y, acc.y);
        acc.z = fmaf(w, v.z, acc.z);
        acc.w = fmaf(w, v.w, acc.w);
    }
    *reinterpret_cast<float4*>(&part[((size_t)b * 4 + ch) * Oc + o0]) = acc;
}

// ---------------- K4: reduce 4 partials -> out ----------------
__global__ __launch_bounds__(256) void k4_reduce(const float* __restrict__ part,
                                                 float* __restrict__ out) {
    const int b = blockIdx.x;
    const int o0 = threadIdx.x * 4;
    float4 a = *reinterpret_cast<const float4*>(&part[((size_t)b * 4 + 0) * Oc + o0]);
    float4 c1 = *reinterpret_cast<const float4*>(&part[((size_t)b * 4 + 1) * Oc + o0]);
    float4 c2 = *reinterpret_cast<const float4*>(&part[((size_t)b * 4 + 2) * Oc + o0]);
    float4 c3 = *reinterpret_cast<const float4*>(&part[((size_t)b * 4 + 3) * Oc + o0]);
    a.x += c1.x + c2.x + c3.x;
    a.y += c1.y + c2.y + c3.y;
    a.z += c1.z + c2.z + c3.z;
    a.w += c1.w + c2.w + c3.w;
    *reinterpret_cast<float4*>(&out[(size_t)b * Oc + o0]) = a;
}

extern "C" void kernel_launch(void* const* d_in, const int* in_sizes, int n_in,
                              void* d_out, int out_size, void* d_ws, size_t ws_size,
                              hipStream_t stream) {
    (void)in_sizes; (void)n_in; (void)out_size; (void)ws_size;
    const float* x    = (const float*)d_in[0];
    const float* Win  = (const float*)d_in[1];
    const float* Wout = (const float*)d_in[2];
    float* out = (float*)d_out;

    float* S    = (float*)d_ws + WS_SCORES;
    u32*   sel  = (u32*)d_ws + WS_SEL;
    float* part = (float*)d_ws + WS_PART;
    f16*   xhi  = (f16*)((u32*)d_ws + WS_XHI);
    f16*   xlo  = (f16*)((u32*)d_ws + WS_XLO);

    static bool attr_set = false;
    if (!attr_set) {
        hipFuncSetAttribute((const void*)k2_select,
                            hipFuncAttributeMaxDynamicSharedMemorySize, K2_LDS_BYTES);
        attr_set = true;
    }

    kx_split<<<32, 512, 0, stream>>>(x, xhi, xlo);
    k1_mfma<<<Hc / 128, 512, 0, stream>>>(Win, xhi, xlo, S);
    k2_select<<<Bc, 1024, K2_LDS_BYTES, stream>>>(S, sel);
    k3_gather<<<Bc * 4, 256, 0, stream>>>(S, Wout, sel, part);
    k4_reduce<<<Bc, 256, 0, stream>>>(part, out);
}